// Round 4
// baseline (275.718 us; speedup 1.0000x reference)
//
#include <hip/hip_runtime.h>

// L=4096, N=B=64. CH=8 -> CN=512 chunks; GC=16 chunks/group -> NG=32 groups.
#define TL 4096
#define NB 64
#define CH 8
#define CN 512
#define GC 16
#define NG 32
#define AS 72          // LDS row stride (bf16 elems): 144 B, odd 16B-groups -> conflict-free b128

typedef __attribute__((ext_vector_type(8))) short short8;
typedef __attribute__((ext_vector_type(4))) short short4v;
typedef __attribute__((ext_vector_type(4))) float floatx4;

__device__ inline floatx4 mfma_bf16(short8 a, short8 b, floatx4 c) {
    return __builtin_amdgcn_mfma_f32_16x16x32_bf16(a, b, c, 0, 0, 0);
}

// fp32 -> (hi, lo) bf16 pair, RNE both. x ~= hi + lo to ~2^-17 rel.
__device__ inline void split_bf16(float x, short& h, short& l) {
    union { float f; unsigned u; } v; v.f = x;
    unsigned uh = v.u + 0x7FFFu + ((v.u >> 16) & 1u);
    h = (short)(uh >> 16);
    union { unsigned u; float f; } hv; hv.u = ((unsigned)(unsigned short)h) << 16;
    float r = x - hv.f;
    union { float f; unsigned u; } rv; rv.f = r;
    unsigned ul = rv.u + 0x7FFFu + ((rv.u >> 16) & 1u);
    l = (short)(ul >> 16);
}

// ---------------------------------------------------------------------------
// K1 (phase1, R1-verbatim): per chunk c, forward S <- A[t] S, V <- A[t] V + u_t.
// Emits PT[c]=S^T ([chunk-entry][exit]), VT[c]=V^T ([batch][state]) fp32.
// ---------------------------------------------------------------------------
__global__ __launch_bounds__(256, 2)
void hippo_phase1(const float* __restrict__ inp, const float* __restrict__ Ag,
                  const float* __restrict__ Bst,
                  float* __restrict__ PT, float* __restrict__ VT)
{
    __shared__ short Ah[NB][AS], Al[NB][AS];
    __shared__ short SBh[NB][AS], SBl[NB][AS];
    __shared__ short VBh[NB][AS], VBl[NB][AS];
    __shared__ float btl[NB], itl[NB];

    const int tid  = threadIdx.x;
    const int c    = blockIdx.x;
    const int t0   = c * CH;
    const int w    = tid >> 6, lane = tid & 63;
    const int quad = lane >> 4, l15 = lane & 15;

#pragma unroll
    for (int q = 0; q < 16; ++q) {
        int f = tid + q * 256;
        int n = f >> 6, k = f & 63;
        SBh[n][k] = (n == k) ? (short)0x3F80 : (short)0;
        SBl[n][k] = 0; VBh[n][k] = 0; VBl[n][k] = 0;
    }

    float4 pre[4];
    {
        const float4* Ap = (const float4*)(Ag + (size_t)t0 * 4096);
#pragma unroll
        for (int q = 0; q < 4; ++q) pre[q] = Ap[tid + q * 256];
    }
    floatx4 accS[4], accV[4];

    for (int s = 0; s < CH; ++s) {
        int t = t0 + s;
#pragma unroll
        for (int q = 0; q < 4; ++q) {
            int f = tid + q * 256;
            int m = f >> 4, k0 = (f & 15) * 4;
            float vv[4] = {pre[q].x, pre[q].y, pre[q].z, pre[q].w};
            short4v h4, l4;
#pragma unroll
            for (int r = 0; r < 4; ++r) { short hh, ll; split_bf16(vv[r], hh, ll); h4[r]=hh; l4[r]=ll; }
            *(short4v*)&Ah[m][k0] = h4;
            *(short4v*)&Al[m][k0] = l4;
        }
        if (tid < 64) { btl[tid] = Bst[(size_t)t*64 + tid]; itl[tid] = inp[(size_t)t*64 + tid]; }
        if (s + 1 < CH) {
            const float4* Ap = (const float4*)(Ag + (size_t)(t+1) * 4096);
#pragma unroll
            for (int q = 0; q < 4; ++q) pre[q] = Ap[tid + q * 256];
        }
        __syncthreads();

#pragma unroll
        for (int ni = 0; ni < 4; ++ni) {
            float ib = itl[16*ni + l15];
#pragma unroll
            for (int r = 0; r < 4; ++r) {
                accS[ni][r] = 0.0f;
                accV[ni][r] = btl[16*w + 4*quad + r] * ib;
            }
        }
#pragma unroll
        for (int kc = 0; kc < 2; ++kc) {
            int ko = 32*kc + 8*quad;
            short8 aH = *(const short8*)&Ah[16*w + l15][ko];
            short8 aL = *(const short8*)&Al[16*w + l15][ko];
#pragma unroll
            for (int ni = 0; ni < 4; ++ni) {
                int n = 16*ni + l15;
                short8 sH = *(const short8*)&SBh[n][ko];
                short8 sL = *(const short8*)&SBl[n][ko];
                accS[ni] = mfma_bf16(aH, sH, accS[ni]);
                accS[ni] = mfma_bf16(aH, sL, accS[ni]);
                accS[ni] = mfma_bf16(aL, sH, accS[ni]);
                short8 vH = *(const short8*)&VBh[n][ko];
                short8 vL = *(const short8*)&VBl[n][ko];
                accV[ni] = mfma_bf16(aH, vH, accV[ni]);
                accV[ni] = mfma_bf16(aH, vL, accV[ni]);
                accV[ni] = mfma_bf16(aL, vH, accV[ni]);
            }
        }
        __syncthreads();

        if (s + 1 < CH) {
#pragma unroll
            for (int ni = 0; ni < 4; ++ni) {
                int cc = 16*ni + l15, r0 = 16*w + 4*quad;
                short4v h4, l4;
#pragma unroll
                for (int r = 0; r < 4; ++r) { short hh,ll; split_bf16(accS[ni][r],hh,ll); h4[r]=hh; l4[r]=ll; }
                *(short4v*)&SBh[cc][r0] = h4; *(short4v*)&SBl[cc][r0] = l4;
#pragma unroll
                for (int r = 0; r < 4; ++r) { short hh,ll; split_bf16(accV[ni][r],hh,ll); h4[r]=hh; l4[r]=ll; }
                *(short4v*)&VBh[cc][r0] = h4; *(short4v*)&VBl[cc][r0] = l4;
            }
            __syncthreads();
        }
    }
#pragma unroll
    for (int ni = 0; ni < 4; ++ni) {
        int cc = 16*ni + l15, r0 = 16*w + 4*quad;
        *(floatx4*)(PT + (size_t)c*4096 + cc*64 + r0) = accS[ni];
        *(floatx4*)(VT + (size_t)c*4096 + cc*64 + r0) = accV[ni];
    }
}

// ---------------------------------------------------------------------------
// K2: per group g (16 chunks), sequential scan. Overwrites PT[c]/VT[c] with
// the EXCLUSIVE in-group prefix (j>=1; j=0 slot untouched, K4 special-cases).
// Writes group totals to GPT/GVT. Combine: Pnew = P_c@Pacc, Vnew = P_c@Vacc+V_c.
// ---------------------------------------------------------------------------
__global__ __launch_bounds__(256, 2)
void hippo_groupscan(float* __restrict__ PT, float* __restrict__ VT,
                     float* __restrict__ GPT, float* __restrict__ GVT)
{
    __shared__ short PAh[NB][AS], PAl[NB][AS];
    __shared__ short PBh[NB][AS], PBl[NB][AS];
    __shared__ short VBh[NB][AS], VBl[NB][AS];

    const int g = blockIdx.x, tid = threadIdx.x;
    const int w = tid>>6, lane = tid&63, quad = lane>>4, l15 = lane&15;
    const int c0 = g * GC;

    floatx4 accP[4], accV[4];

    // j = 0: inclusive = (P_{c0}, V_{c0})
    {
        const float* ptc = PT + (size_t)c0*4096;
        const float* vtc = VT + (size_t)c0*4096;
#pragma unroll
        for (int ni = 0; ni < 4; ++ni) {
            int cc = 16*ni + l15, r0 = 16*w + 4*quad;
            accP[ni] = *(const floatx4*)(ptc + cc*64 + r0);
            accV[ni] = *(const floatx4*)(vtc + cc*64 + r0);
        }
#pragma unroll
        for (int ni = 0; ni < 4; ++ni) {
            int cc = 16*ni + l15, r0 = 16*w + 4*quad;
            short4v h4, l4;
#pragma unroll
            for (int r=0;r<4;++r){short hh,ll;split_bf16(accP[ni][r],hh,ll);h4[r]=hh;l4[r]=ll;}
            *(short4v*)&PBh[cc][r0]=h4; *(short4v*)&PBl[cc][r0]=l4;
#pragma unroll
            for (int r=0;r<4;++r){short hh,ll;split_bf16(accV[ni][r],hh,ll);h4[r]=hh;l4[r]=ll;}
            *(short4v*)&VBh[cc][r0]=h4; *(short4v*)&VBl[cc][r0]=l4;
        }
    }

    for (int j = 1; j < GC; ++j) {
        const int c = c0 + j;
        const float* ptc = PT + (size_t)c*4096;
        const float* vtc = VT + (size_t)c*4096;
        floatx4 vc[4];
#pragma unroll
        for (int ni = 0; ni < 4; ++ni) {
            int cc = 16*ni + l15, r0 = 16*w + 4*quad;
            vc[ni] = *(const floatx4*)(vtc + cc*64 + r0);
        }
        // transpose-stage P_c -> PA ([exit][entry])
#pragma unroll
        for (int q = 0; q < 4; ++q) {
            int f = tid + q*256;
            int k = f & 63, m0 = (f >> 6) * 4;
            float4 v = *(const float4*)(ptc + k*64 + m0);
            float vv[4] = {v.x,v.y,v.z,v.w};
#pragma unroll
            for (int rr = 0; rr < 4; ++rr) { short hh,ll; split_bf16(vv[rr],hh,ll); PAh[m0+rr][k]=hh; PAl[m0+rr][k]=ll; }
        }
        __syncthreads();   // PA staged; prev PB/VB visible; PT[c]/VT[c] consumed

        // write exclusive prefix (inclusive through j-1) in-place
#pragma unroll
        for (int ni = 0; ni < 4; ++ni) {
            int cc = 16*ni + l15, r0 = 16*w + 4*quad;
            *(floatx4*)(PT + (size_t)c*4096 + cc*64 + r0) = accP[ni];
            *(floatx4*)(VT + (size_t)c*4096 + cc*64 + r0) = accV[ni];
        }
        floatx4 nP[4], nV[4];
#pragma unroll
        for (int ni = 0; ni < 4; ++ni) {
            nV[ni] = vc[ni];
            nP[ni][0]=0.f; nP[ni][1]=0.f; nP[ni][2]=0.f; nP[ni][3]=0.f;
        }
#pragma unroll
        for (int kc = 0; kc < 2; ++kc) {
            int ko = 32*kc + 8*quad;
            short8 aH = *(const short8*)&PAh[16*w + l15][ko];
            short8 aL = *(const short8*)&PAl[16*w + l15][ko];
#pragma unroll
            for (int ni = 0; ni < 4; ++ni) {
                int n = 16*ni + l15;
                short8 pH = *(const short8*)&PBh[n][ko];
                short8 pL = *(const short8*)&PBl[n][ko];
                nP[ni] = mfma_bf16(aH,pH,nP[ni]);
                nP[ni] = mfma_bf16(aH,pL,nP[ni]);
                nP[ni] = mfma_bf16(aL,pH,nP[ni]);
                short8 vH = *(const short8*)&VBh[n][ko];
                short8 vL = *(const short8*)&VBl[n][ko];
                nV[ni] = mfma_bf16(aH,vH,nV[ni]);
                nV[ni] = mfma_bf16(aH,vL,nV[ni]);
                nV[ni] = mfma_bf16(aL,vH,nV[ni]);
            }
        }
        __syncthreads();   // PB/VB reads done before overwrite

#pragma unroll
        for (int ni = 0; ni < 4; ++ni) { accP[ni] = nP[ni]; accV[ni] = nV[ni]; }
        if (j + 1 < GC) {
#pragma unroll
            for (int ni = 0; ni < 4; ++ni) {
                int cc = 16*ni + l15, r0 = 16*w + 4*quad;
                short4v h4, l4;
#pragma unroll
                for (int r=0;r<4;++r){short hh,ll;split_bf16(accP[ni][r],hh,ll);h4[r]=hh;l4[r]=ll;}
                *(short4v*)&PBh[cc][r0]=h4; *(short4v*)&PBl[cc][r0]=l4;
#pragma unroll
                for (int r=0;r<4;++r){short hh,ll;split_bf16(accV[ni][r],hh,ll);h4[r]=hh;l4[r]=ll;}
                *(short4v*)&VBh[cc][r0]=h4; *(short4v*)&VBl[cc][r0]=l4;
            }
        }
    }
    // group totals
#pragma unroll
    for (int ni = 0; ni < 4; ++ni) {
        int cc = 16*ni + l15, r0 = 16*w + 4*quad;
        *(floatx4*)(GPT + (size_t)g*4096 + cc*64 + r0) = accP[ni];
        *(floatx4*)(GVT + (size_t)g*4096 + cc*64 + r0) = accV[ni];
    }
}

// ---------------------------------------------------------------------------
// K3: 1 WG. E <- Ghat_P[g] @ E + Ghat_V[g]; EgT[g] = inclusive group prefix.
// ---------------------------------------------------------------------------
__global__ __launch_bounds__(256)
void hippo_superscan(const float* __restrict__ GPT, const float* __restrict__ GVT,
                     float* __restrict__ EgT)
{
    __shared__ short PAh[NB][AS], PAl[NB][AS];
    __shared__ short VBh[NB][AS], VBl[NB][AS];
    const int tid = threadIdx.x;
    const int w = tid>>6, lane = tid&63, quad = lane>>4, l15 = lane&15;

    floatx4 accV[4];
#pragma unroll
    for (int ni = 0; ni < 4; ++ni) {
        int cc = 16*ni + l15, r0 = 16*w + 4*quad;
        accV[ni] = *(const floatx4*)(GVT + cc*64 + r0);
        *(floatx4*)(EgT + cc*64 + r0) = accV[ni];
        short4v h4, l4;
#pragma unroll
        for (int r=0;r<4;++r){short hh,ll;split_bf16(accV[ni][r],hh,ll);h4[r]=hh;l4[r]=ll;}
        *(short4v*)&VBh[cc][r0]=h4; *(short4v*)&VBl[cc][r0]=l4;
    }
    for (int g = 1; g < NG; ++g) {
        const float* gp = GPT + (size_t)g*4096;
        const float* gv = GVT + (size_t)g*4096;
#pragma unroll
        for (int q = 0; q < 4; ++q) {
            int f = tid + q*256;
            int k = f & 63, m0 = (f >> 6) * 4;
            float4 v = *(const float4*)(gp + k*64 + m0);
            float vv[4] = {v.x,v.y,v.z,v.w};
#pragma unroll
            for (int rr=0;rr<4;++rr){short hh,ll;split_bf16(vv[rr],hh,ll);PAh[m0+rr][k]=hh;PAl[m0+rr][k]=ll;}
        }
        __syncthreads();   // PA staged; VB (prev) visible
        floatx4 nV[4];
#pragma unroll
        for (int ni = 0; ni < 4; ++ni) {
            int cc = 16*ni + l15, r0 = 16*w + 4*quad;
            nV[ni] = *(const floatx4*)(gv + cc*64 + r0);
        }
#pragma unroll
        for (int kc = 0; kc < 2; ++kc) {
            int ko = 32*kc + 8*quad;
            short8 aH = *(const short8*)&PAh[16*w + l15][ko];
            short8 aL = *(const short8*)&PAl[16*w + l15][ko];
#pragma unroll
            for (int ni = 0; ni < 4; ++ni) {
                int n = 16*ni + l15;
                short8 vH = *(const short8*)&VBh[n][ko];
                short8 vL = *(const short8*)&VBl[n][ko];
                nV[ni] = mfma_bf16(aH,vH,nV[ni]);
                nV[ni] = mfma_bf16(aH,vL,nV[ni]);
                nV[ni] = mfma_bf16(aL,vH,nV[ni]);
            }
        }
        __syncthreads();   // VB reads done
#pragma unroll
        for (int ni = 0; ni < 4; ++ni) {
            int cc = 16*ni + l15, r0 = 16*w + 4*quad;
            accV[ni] = nV[ni];
            *(floatx4*)(EgT + (size_t)g*4096 + cc*64 + r0) = accV[ni];
            short4v h4, l4;
#pragma unroll
            for (int r=0;r<4;++r){short hh,ll;split_bf16(accV[ni][r],hh,ll);h4[r]=hh;l4[r]=ll;}
            *(short4v*)&VBh[cc][r0]=h4; *(short4v*)&VBl[cc][r0]=l4;
        }
    }
}

// ---------------------------------------------------------------------------
// K4 (phase3 + entry): X_enter = Pe_c @ Eg[g-1] + Ve_c, then 8 recurrence
// steps x <- A[t] x + u_t with coalesced float4 out stores.
// ---------------------------------------------------------------------------
__global__ __launch_bounds__(256, 2)
void hippo_phase3(const float* __restrict__ inp, const float* __restrict__ Ag,
                  const float* __restrict__ Bst,
                  const float* __restrict__ PeT, const float* __restrict__ VeT,
                  const float* __restrict__ EgT, float* __restrict__ out)
{
    __shared__ short Ah[NB][AS], Al[NB][AS];
    __shared__ short XBh[NB][AS], XBl[NB][AS];
    __shared__ short EBh[NB][AS], EBl[NB][AS];
    __shared__ float btl[NB], itl[NB];

    const int tid = threadIdx.x, c = blockIdx.x, t0 = c * CH;
    const int g = c >> 4, j = c & (GC - 1);
    const int w = tid>>6, lane = tid&63, quad = lane>>4, l15 = lane&15;

    // prefetch first A tile early
    float4 pre[4];
    {
        const float4* Ap = (const float4*)(Ag + (size_t)t0 * 4096);
#pragma unroll
        for (int q = 0; q < 4; ++q) pre[q] = Ap[tid + q * 256];
    }

    // ---- entering state into XB ([b][state], split) ----
    if (c == 0) {
#pragma unroll
        for (int q = 0; q < 16; ++q) { int f = tid + q*256; XBh[f>>6][f&63] = 0; XBl[f>>6][f&63] = 0; }
    } else if (j == 0 || g == 0) {
        const float* e = (j == 0) ? (EgT + (size_t)(g-1)*4096) : (VeT + (size_t)c*4096);
#pragma unroll
        for (int q = 0; q < 4; ++q) {
            int f = tid + q*256; int b = f>>4, k0 = (f&15)*4;
            float4 v = *(const float4*)(e + b*64 + k0);
            float va[4] = {v.x,v.y,v.z,v.w};
            short4v h4, l4;
#pragma unroll
            for (int r=0;r<4;++r){short hh,ll;split_bf16(va[r],hh,ll);h4[r]=hh;l4[r]=ll;}
            *(short4v*)&XBh[b][k0] = h4; *(short4v*)&XBl[b][k0] = l4;
        }
    } else {
        // X_enter = Pe @ Eg[g-1] + Ve : Pe transpose-staged into Ah/Al (reused),
        // Eg direct into EB, acc init from Ve (C-layout).
        const float* pe = PeT + (size_t)c*4096;
        const float* eg = EgT + (size_t)(g-1)*4096;
#pragma unroll
        for (int q = 0; q < 4; ++q) {
            int f = tid + q*256;
            int k = f & 63, m0 = (f >> 6) * 4;
            float4 v = *(const float4*)(pe + k*64 + m0);
            float vv[4] = {v.x,v.y,v.z,v.w};
#pragma unroll
            for (int rr=0;rr<4;++rr){short hh,ll;split_bf16(vv[rr],hh,ll);Ah[m0+rr][k]=hh;Al[m0+rr][k]=ll;}
        }
#pragma unroll
        for (int q = 0; q < 4; ++q) {
            int f = tid + q*256; int b = f>>4, k0 = (f&15)*4;
            float4 v = *(const float4*)(eg + b*64 + k0);
            float va[4] = {v.x,v.y,v.z,v.w};
            short4v h4, l4;
#pragma unroll
            for (int r=0;r<4;++r){short hh,ll;split_bf16(va[r],hh,ll);h4[r]=hh;l4[r]=ll;}
            *(short4v*)&EBh[b][k0] = h4; *(short4v*)&EBl[b][k0] = l4;
        }
        __syncthreads();
        const float* ve = VeT + (size_t)c*4096;
        floatx4 ax[4];
#pragma unroll
        for (int ni = 0; ni < 4; ++ni) {
            int cc = 16*ni + l15, r0 = 16*w + 4*quad;
            ax[ni] = *(const floatx4*)(ve + cc*64 + r0);
        }
#pragma unroll
        for (int kc = 0; kc < 2; ++kc) {
            int ko = 32*kc + 8*quad;
            short8 aH = *(const short8*)&Ah[16*w + l15][ko];
            short8 aL = *(const short8*)&Al[16*w + l15][ko];
#pragma unroll
            for (int ni = 0; ni < 4; ++ni) {
                int n = 16*ni + l15;
                short8 eH = *(const short8*)&EBh[n][ko];
                short8 eL = *(const short8*)&EBl[n][ko];
                ax[ni] = mfma_bf16(aH,eH,ax[ni]);
                ax[ni] = mfma_bf16(aH,eL,ax[ni]);
                ax[ni] = mfma_bf16(aL,eH,ax[ni]);
            }
        }
        __syncthreads();   // Ah/Al + EB reads done before main loop restages Ah/Al
#pragma unroll
        for (int ni = 0; ni < 4; ++ni) {
            int cc = 16*ni + l15, r0 = 16*w + 4*quad;
            short4v h4, l4;
#pragma unroll
            for (int r=0;r<4;++r){short hh,ll;split_bf16(ax[ni][r],hh,ll);h4[r]=hh;l4[r]=ll;}
            *(short4v*)&XBh[cc][r0] = h4; *(short4v*)&XBl[cc][r0] = l4;
        }
    }

    floatx4 acc[4];
    for (int s = 0; s < CH; ++s) {
        int t = t0 + s;
#pragma unroll
        for (int q = 0; q < 4; ++q) {
            int f = tid + q*256; int m = f>>4, k0 = (f&15)*4;
            float vv[4] = {pre[q].x,pre[q].y,pre[q].z,pre[q].w};
            short4v h4, l4;
#pragma unroll
            for (int r=0;r<4;++r){short hh,ll;split_bf16(vv[r],hh,ll);h4[r]=hh;l4[r]=ll;}
            *(short4v*)&Ah[m][k0] = h4; *(short4v*)&Al[m][k0] = l4;
        }
        if (tid < 64) { btl[tid] = Bst[(size_t)t*64 + tid]; itl[tid] = inp[(size_t)t*64 + tid]; }
        if (s + 1 < CH) {
            const float4* Ap = (const float4*)(Ag + (size_t)(t+1) * 4096);
#pragma unroll
            for (int q = 0; q < 4; ++q) pre[q] = Ap[tid + q * 256];
        }
        __syncthreads();

#pragma unroll
        for (int ni = 0; ni < 4; ++ni) {
            float ib = itl[16*ni + l15];
#pragma unroll
            for (int r = 0; r < 4; ++r) acc[ni][r] = btl[16*w + 4*quad + r] * ib;
        }
#pragma unroll
        for (int kc = 0; kc < 2; ++kc) {
            int ko = 32*kc + 8*quad;
            short8 aH = *(const short8*)&Ah[16*w + l15][ko];
            short8 aL = *(const short8*)&Al[16*w + l15][ko];
#pragma unroll
            for (int ni = 0; ni < 4; ++ni) {
                int n = 16*ni + l15;
                short8 xH = *(const short8*)&XBh[n][ko];
                short8 xL = *(const short8*)&XBl[n][ko];
                acc[ni] = mfma_bf16(aH, xH, acc[ni]);
                acc[ni] = mfma_bf16(aH, xL, acc[ni]);
                acc[ni] = mfma_bf16(aL, xH, acc[ni]);
            }
        }
        __syncthreads();
#pragma unroll
        for (int ni = 0; ni < 4; ++ni) {
            int cc = 16*ni + l15, r0 = 16*w + 4*quad;
            *(floatx4*)(out + (size_t)t*4096 + cc*64 + r0) = acc[ni];
            if (s + 1 < CH) {
                short4v h4, l4;
#pragma unroll
                for (int r=0;r<4;++r){short hh,ll;split_bf16(acc[ni][r],hh,ll);h4[r]=hh;l4[r]=ll;}
                *(short4v*)&XBh[cc][r0] = h4; *(short4v*)&XBl[cc][r0] = l4;
            }
        }
        if (s + 1 < CH) __syncthreads();
    }
}

extern "C" void kernel_launch(void* const* d_in, const int* in_sizes, int n_in,
                              void* d_out, int out_size, void* d_ws, size_t ws_size,
                              hipStream_t stream)
{
    const float* inp = (const float*)d_in[0];   // (L, B)
    const float* A   = (const float*)d_in[1];   // (L, N, N)
    const float* Bst = (const float*)d_in[2];   // (L, N)
    float* out = (float*)d_out;                  // (L, B, N)
    float* ws  = (float*)d_ws;                   // ~17.4 MB used (<= R1's proven 33.5 MB)

    float* PT  = ws;                                   // 512*4096
    float* VT  = ws + (size_t)CN * 4096;               // 512*4096
    float* GPT = ws + (size_t)2 * CN * 4096;           // 32*4096
    float* GVT = GPT + (size_t)NG * 4096;              // 32*4096
    float* EgT = GVT + (size_t)NG * 4096;              // 32*4096

    hippo_phase1<<<CN, 256, 0, stream>>>(inp, A, Bst, PT, VT);
    hippo_groupscan<<<NG, 256, 0, stream>>>(PT, VT, GPT, GVT);
    hippo_superscan<<<1, 256, 0, stream>>>(GPT, GVT, EgT);
    hippo_phase3<<<CN, 256, 0, stream>>>(inp, A, Bst, PT, VT, EgT, out);
}

// Round 5
// 253.152 us; speedup vs baseline: 1.0891x; 1.0891x over previous
//
#include <hip/hip_runtime.h>

// L=4096, N=B=64. CH=8 -> CN=512 chunks; GC=16 chunks/group -> NG=32 groups.
#define TL 4096
#define NB 64
#define CH 8
#define CN 512
#define GC 16
#define NG 32
#define AS 72          // LDS row stride (bf16 elems): 144 B, odd 16B-groups -> conflict-free b128

typedef __attribute__((ext_vector_type(8))) short short8;
typedef __attribute__((ext_vector_type(4))) short short4v;
typedef __attribute__((ext_vector_type(4))) float floatx4;

__device__ inline floatx4 mfma_bf16(short8 a, short8 b, floatx4 c) {
    return __builtin_amdgcn_mfma_f32_16x16x32_bf16(a, b, c, 0, 0, 0);
}

// fp32 -> (hi, lo) bf16 pair, RNE both. x ~= hi + lo to ~2^-17 rel.
__device__ inline void split_bf16(float x, short& h, short& l) {
    union { float f; unsigned u; } v; v.f = x;
    unsigned uh = v.u + 0x7FFFu + ((v.u >> 16) & 1u);
    h = (short)(uh >> 16);
    union { unsigned u; float f; } hv; hv.u = ((unsigned)(unsigned short)h) << 16;
    float r = x - hv.f;
    union { float f; unsigned u; } rv; rv.f = r;
    unsigned ul = rv.u + 0x7FFFu + ((rv.u >> 16) & 1u);
    l = (short)(ul >> 16);
}

__device__ inline void split8(float4 f0, float4 f1, short8& h, short8& l) {
    float v[8] = {f0.x,f0.y,f0.z,f0.w,f1.x,f1.y,f1.z,f1.w};
#pragma unroll
    for (int i = 0; i < 8; ++i) { short hh, ll; split_bf16(v[i], hh, ll); h[i]=hh; l[i]=ll; }
}

// ---------------------------------------------------------------------------
// K1 (phase1): per chunk c, forward S <- A[t] S, V <- A[t] V + u_t.
// Emits PT[c]=S^T ([chunk-entry][exit]), VT[c]=V^T ([batch][state]) fp32.
// ---------------------------------------------------------------------------
__global__ __launch_bounds__(256, 2)
void hippo_phase1(const float* __restrict__ inp, const float* __restrict__ Ag,
                  const float* __restrict__ Bst,
                  float* __restrict__ PT, float* __restrict__ VT)
{
    __shared__ short Ah[NB][AS], Al[NB][AS];
    __shared__ short SBh[NB][AS], SBl[NB][AS];
    __shared__ short VBh[NB][AS], VBl[NB][AS];
    __shared__ float btl[NB], itl[NB];

    const int tid  = threadIdx.x;
    const int c    = blockIdx.x;
    const int t0   = c * CH;
    const int w    = tid >> 6, lane = tid & 63;
    const int quad = lane >> 4, l15 = lane & 15;

#pragma unroll
    for (int q = 0; q < 16; ++q) {
        int f = tid + q * 256;
        int n = f >> 6, k = f & 63;
        SBh[n][k] = (n == k) ? (short)0x3F80 : (short)0;
        SBl[n][k] = 0; VBh[n][k] = 0; VBl[n][k] = 0;
    }

    float4 pre[4];
    {
        const float4* Ap = (const float4*)(Ag + (size_t)t0 * 4096);
#pragma unroll
        for (int q = 0; q < 4; ++q) pre[q] = Ap[tid + q * 256];
    }
    floatx4 accS[4], accV[4];

    for (int s = 0; s < CH; ++s) {
        int t = t0 + s;
#pragma unroll
        for (int q = 0; q < 4; ++q) {
            int f = tid + q * 256;
            int m = f >> 4, k0 = (f & 15) * 4;
            float vv[4] = {pre[q].x, pre[q].y, pre[q].z, pre[q].w};
            short4v h4, l4;
#pragma unroll
            for (int r = 0; r < 4; ++r) { short hh, ll; split_bf16(vv[r], hh, ll); h4[r]=hh; l4[r]=ll; }
            *(short4v*)&Ah[m][k0] = h4;
            *(short4v*)&Al[m][k0] = l4;
        }
        if (tid < 64) { btl[tid] = Bst[(size_t)t*64 + tid]; itl[tid] = inp[(size_t)t*64 + tid]; }
        if (s + 1 < CH) {
            const float4* Ap = (const float4*)(Ag + (size_t)(t+1) * 4096);
#pragma unroll
            for (int q = 0; q < 4; ++q) pre[q] = Ap[tid + q * 256];
        }
        __syncthreads();

#pragma unroll
        for (int ni = 0; ni < 4; ++ni) {
            float ib = itl[16*ni + l15];
#pragma unroll
            for (int r = 0; r < 4; ++r) {
                accS[ni][r] = 0.0f;
                accV[ni][r] = btl[16*w + 4*quad + r] * ib;
            }
        }
#pragma unroll
        for (int kc = 0; kc < 2; ++kc) {
            int ko = 32*kc + 8*quad;
            short8 aH = *(const short8*)&Ah[16*w + l15][ko];
            short8 aL = *(const short8*)&Al[16*w + l15][ko];
#pragma unroll
            for (int ni = 0; ni < 4; ++ni) {
                int n = 16*ni + l15;
                short8 sH = *(const short8*)&SBh[n][ko];
                short8 sL = *(const short8*)&SBl[n][ko];
                accS[ni] = mfma_bf16(aH, sH, accS[ni]);
                accS[ni] = mfma_bf16(aH, sL, accS[ni]);
                accS[ni] = mfma_bf16(aL, sH, accS[ni]);
                short8 vH = *(const short8*)&VBh[n][ko];
                short8 vL = *(const short8*)&VBl[n][ko];
                accV[ni] = mfma_bf16(aH, vH, accV[ni]);
                accV[ni] = mfma_bf16(aH, vL, accV[ni]);
                accV[ni] = mfma_bf16(aL, vH, accV[ni]);
            }
        }
        __syncthreads();

        if (s + 1 < CH) {
#pragma unroll
            for (int ni = 0; ni < 4; ++ni) {
                int cc = 16*ni + l15, r0 = 16*w + 4*quad;
                short4v h4, l4;
#pragma unroll
                for (int r = 0; r < 4; ++r) { short hh,ll; split_bf16(accS[ni][r],hh,ll); h4[r]=hh; l4[r]=ll; }
                *(short4v*)&SBh[cc][r0] = h4; *(short4v*)&SBl[cc][r0] = l4;
#pragma unroll
                for (int r = 0; r < 4; ++r) { short hh,ll; split_bf16(accV[ni][r],hh,ll); h4[r]=hh; l4[r]=ll; }
                *(short4v*)&VBh[cc][r0] = h4; *(short4v*)&VBl[cc][r0] = l4;
            }
            __syncthreads();
        }
    }
#pragma unroll
    for (int ni = 0; ni < 4; ++ni) {
        int cc = 16*ni + l15, r0 = 16*w + 4*quad;
        *(floatx4*)(PT + (size_t)c*4096 + cc*64 + r0) = accS[ni];
        *(floatx4*)(VT + (size_t)c*4096 + cc*64 + r0) = accV[ni];
    }
}

// ---------------------------------------------------------------------------
// K2 (pipelined): per group g, sequential scan over 16 chunks. Overwrites
// PT[c]/VT[c] with the EXCLUSIVE in-group prefix (j>=1). Group totals:
// GPR[g] = P row-major ([exit][entry], for K3's direct A-frags), GVT[g] = V^T.
// Next iteration's global loads issue before this iteration's MFMA.
// ---------------------------------------------------------------------------
__global__ __launch_bounds__(256, 2)
void hippo_groupscan(float* __restrict__ PT, float* __restrict__ VT,
                     float* __restrict__ GPR, float* __restrict__ GVT)
{
    __shared__ short PAh[NB][AS], PAl[NB][AS];
    __shared__ short PBh[NB][AS], PBl[NB][AS];
    __shared__ short VBh[NB][AS], VBl[NB][AS];

    const int g = blockIdx.x, tid = threadIdx.x;
    const int w = tid>>6, lane = tid&63, quad = lane>>4, l15 = lane&15;
    const int c0 = g * GC;

    floatx4 accP[4], accV[4];

    // j=0: inclusive = (P_{c0}, V_{c0}); stage into PB/VB
    {
        const float* ptc = PT + (size_t)c0*4096;
        const float* vtc = VT + (size_t)c0*4096;
#pragma unroll
        for (int ni = 0; ni < 4; ++ni) {
            int cc = 16*ni + l15, r0 = 16*w + 4*quad;
            accP[ni] = *(const floatx4*)(ptc + cc*64 + r0);
            accV[ni] = *(const floatx4*)(vtc + cc*64 + r0);
        }
#pragma unroll
        for (int ni = 0; ni < 4; ++ni) {
            int cc = 16*ni + l15, r0 = 16*w + 4*quad;
            short4v h4, l4;
#pragma unroll
            for (int r=0;r<4;++r){short hh,ll;split_bf16(accP[ni][r],hh,ll);h4[r]=hh;l4[r]=ll;}
            *(short4v*)&PBh[cc][r0]=h4; *(short4v*)&PBl[cc][r0]=l4;
#pragma unroll
            for (int r=0;r<4;++r){short hh,ll;split_bf16(accV[ni][r],hh,ll);h4[r]=hh;l4[r]=ll;}
            *(short4v*)&VBh[cc][r0]=h4; *(short4v*)&VBl[cc][r0]=l4;
        }
    }
    // prefetch j=1
    float4 pcur[4]; floatx4 vcur[4];
    {
        const float* ptc = PT + (size_t)(c0+1)*4096;
        const float* vtc = VT + (size_t)(c0+1)*4096;
#pragma unroll
        for (int q = 0; q < 4; ++q) {
            int f = tid + q*256;
            int k = f & 63, m0 = (f >> 6) * 4;
            pcur[q] = *(const float4*)(ptc + k*64 + m0);
        }
#pragma unroll
        for (int ni = 0; ni < 4; ++ni) {
            int cc = 16*ni + l15, r0 = 16*w + 4*quad;
            vcur[ni] = *(const floatx4*)(vtc + cc*64 + r0);
        }
    }

    for (int j = 1; j < GC; ++j) {
        const int c = c0 + j;
        // prefetch j+1 (independent of the scan chain)
        float4 pnx[4]; floatx4 vnx[4];
        if (j + 1 < GC) {
            const float* ptn = PT + (size_t)(c+1)*4096;
            const float* vtn = VT + (size_t)(c+1)*4096;
#pragma unroll
            for (int q = 0; q < 4; ++q) {
                int f = tid + q*256;
                int k = f & 63, m0 = (f >> 6) * 4;
                pnx[q] = *(const float4*)(ptn + k*64 + m0);
            }
#pragma unroll
            for (int ni = 0; ni < 4; ++ni) {
                int cc = 16*ni + l15, r0 = 16*w + 4*quad;
                vnx[ni] = *(const floatx4*)(vtn + cc*64 + r0);
            }
        }
        // transpose-stage P_c -> PA ([exit][entry]) from prefetched regs
#pragma unroll
        for (int q = 0; q < 4; ++q) {
            int f = tid + q*256;
            int k = f & 63, m0 = (f >> 6) * 4;
            float vv[4] = {pcur[q].x,pcur[q].y,pcur[q].z,pcur[q].w};
#pragma unroll
            for (int rr = 0; rr < 4; ++rr) { short hh,ll; split_bf16(vv[rr],hh,ll); PAh[m0+rr][k]=hh; PAl[m0+rr][k]=ll; }
        }
        __syncthreads();   // PA staged; PB/VB (prefix j-1) visible

        // write exclusive prefix in-place (slot c fully consumed already)
#pragma unroll
        for (int ni = 0; ni < 4; ++ni) {
            int cc = 16*ni + l15, r0 = 16*w + 4*quad;
            *(floatx4*)(PT + (size_t)c*4096 + cc*64 + r0) = accP[ni];
            *(floatx4*)(VT + (size_t)c*4096 + cc*64 + r0) = accV[ni];
        }
        floatx4 nP[4], nV[4];
#pragma unroll
        for (int ni = 0; ni < 4; ++ni) {
            nV[ni] = vcur[ni];
            nP[ni][0]=0.f; nP[ni][1]=0.f; nP[ni][2]=0.f; nP[ni][3]=0.f;
        }
#pragma unroll
        for (int kc = 0; kc < 2; ++kc) {
            int ko = 32*kc + 8*quad;
            short8 aH = *(const short8*)&PAh[16*w + l15][ko];
            short8 aL = *(const short8*)&PAl[16*w + l15][ko];
#pragma unroll
            for (int ni = 0; ni < 4; ++ni) {
                int n = 16*ni + l15;
                short8 pH = *(const short8*)&PBh[n][ko];
                short8 pL = *(const short8*)&PBl[n][ko];
                nP[ni] = mfma_bf16(aH,pH,nP[ni]);
                nP[ni] = mfma_bf16(aH,pL,nP[ni]);
                nP[ni] = mfma_bf16(aL,pH,nP[ni]);
                short8 vH = *(const short8*)&VBh[n][ko];
                short8 vL = *(const short8*)&VBl[n][ko];
                nV[ni] = mfma_bf16(aH,vH,nV[ni]);
                nV[ni] = mfma_bf16(aH,vL,nV[ni]);
                nV[ni] = mfma_bf16(aL,vH,nV[ni]);
            }
        }
        __syncthreads();   // PB/VB reads done before restage

#pragma unroll
        for (int ni = 0; ni < 4; ++ni) { accP[ni] = nP[ni]; accV[ni] = nV[ni]; }
        if (j + 1 < GC) {
#pragma unroll
            for (int ni = 0; ni < 4; ++ni) {
                int cc = 16*ni + l15, r0 = 16*w + 4*quad;
                short4v h4, l4;
#pragma unroll
                for (int r=0;r<4;++r){short hh,ll;split_bf16(accP[ni][r],hh,ll);h4[r]=hh;l4[r]=ll;}
                *(short4v*)&PBh[cc][r0]=h4; *(short4v*)&PBl[cc][r0]=l4;
#pragma unroll
                for (int r=0;r<4;++r){short hh,ll;split_bf16(accV[ni][r],hh,ll);h4[r]=hh;l4[r]=ll;}
                *(short4v*)&VBh[cc][r0]=h4; *(short4v*)&VBl[cc][r0]=l4;
            }
#pragma unroll
            for (int q = 0; q < 4; ++q) pcur[q] = pnx[q];
#pragma unroll
            for (int ni = 0; ni < 4; ++ni) vcur[ni] = vnx[ni];
        }
    }
    // group totals: GVT = V^T (C-layout contiguous), GPR = P row-major scatter
#pragma unroll
    for (int ni = 0; ni < 4; ++ni) {
        int cc = 16*ni + l15, r0 = 16*w + 4*quad;
        *(floatx4*)(GVT + (size_t)g*4096 + cc*64 + r0) = accV[ni];
#pragma unroll
        for (int r = 0; r < 4; ++r)
            GPR[(size_t)g*4096 + (size_t)(r0 + r)*64 + cc] = accP[ni][r];
    }
}

// ---------------------------------------------------------------------------
// K3 (pipelined): 1 WG. E <- GP[g] @ E + GV[g]; EgT[g] = inclusive prefix.
// A-frags load DIRECTLY from row-major GPR (no LDS transpose); next g's
// loads issue before this g's MFMA. Only E round-trips through LDS.
// ---------------------------------------------------------------------------
__global__ __launch_bounds__(256)
void hippo_superscan(const float* __restrict__ GPR, const float* __restrict__ GVT,
                     float* __restrict__ EgT)
{
    __shared__ short VBh[NB][AS], VBl[NB][AS];
    const int tid = threadIdx.x;
    const int w = tid>>6, lane = tid&63, quad = lane>>4, l15 = lane&15;
    const int m = 16*w + l15;

    floatx4 accV[4];
#pragma unroll
    for (int ni = 0; ni < 4; ++ni) {
        int cc = 16*ni + l15, r0 = 16*w + 4*quad;
        accV[ni] = *(const floatx4*)(GVT + cc*64 + r0);
        *(floatx4*)(EgT + cc*64 + r0) = accV[ni];
        short4v h4, l4;
#pragma unroll
        for (int r=0;r<4;++r){short hh,ll;split_bf16(accV[ni][r],hh,ll);h4[r]=hh;l4[r]=ll;}
        *(short4v*)&VBh[cc][r0]=h4; *(short4v*)&VBl[cc][r0]=l4;
    }
    // prefetch g=1
    float4 pf[4]; floatx4 vcur[4];
    {
        const float* gp = GPR + 4096;
        pf[0] = *(const float4*)(gp + m*64 + 8*quad);
        pf[1] = *(const float4*)(gp + m*64 + 8*quad + 4);
        pf[2] = *(const float4*)(gp + m*64 + 32 + 8*quad);
        pf[3] = *(const float4*)(gp + m*64 + 32 + 8*quad + 4);
        const float* gv = GVT + 4096;
#pragma unroll
        for (int ni = 0; ni < 4; ++ni) {
            int cc = 16*ni + l15, r0 = 16*w + 4*quad;
            vcur[ni] = *(const floatx4*)(gv + cc*64 + r0);
        }
    }

    for (int g = 1; g < NG; ++g) {
        float4 pn[4]; floatx4 vnx[4];
        if (g + 1 < NG) {
            const float* gp = GPR + (size_t)(g+1)*4096;
            pn[0] = *(const float4*)(gp + m*64 + 8*quad);
            pn[1] = *(const float4*)(gp + m*64 + 8*quad + 4);
            pn[2] = *(const float4*)(gp + m*64 + 32 + 8*quad);
            pn[3] = *(const float4*)(gp + m*64 + 32 + 8*quad + 4);
            const float* gv = GVT + (size_t)(g+1)*4096;
#pragma unroll
            for (int ni = 0; ni < 4; ++ni) {
                int cc = 16*ni + l15, r0 = 16*w + 4*quad;
                vnx[ni] = *(const floatx4*)(gv + cc*64 + r0);
            }
        }
        short8 aH[2], aL[2];
        split8(pf[0], pf[1], aH[0], aL[0]);
        split8(pf[2], pf[3], aH[1], aL[1]);
        floatx4 nV[4];
#pragma unroll
        for (int ni = 0; ni < 4; ++ni) nV[ni] = vcur[ni];
        __syncthreads();   // VB (prefix g-1) visible
#pragma unroll
        for (int kc = 0; kc < 2; ++kc) {
            int ko = 32*kc + 8*quad;
#pragma unroll
            for (int ni = 0; ni < 4; ++ni) {
                int n = 16*ni + l15;
                short8 vH = *(const short8*)&VBh[n][ko];
                short8 vL = *(const short8*)&VBl[n][ko];
                nV[ni] = mfma_bf16(aH[kc],vH,nV[ni]);
                nV[ni] = mfma_bf16(aH[kc],vL,nV[ni]);
                nV[ni] = mfma_bf16(aL[kc],vH,nV[ni]);
            }
        }
        __syncthreads();   // VB reads done
#pragma unroll
        for (int ni = 0; ni < 4; ++ni) {
            int cc = 16*ni + l15, r0 = 16*w + 4*quad;
            accV[ni] = nV[ni];
            *(floatx4*)(EgT + (size_t)g*4096 + cc*64 + r0) = accV[ni];
            short4v h4, l4;
#pragma unroll
            for (int r=0;r<4;++r){short hh,ll;split_bf16(accV[ni][r],hh,ll);h4[r]=hh;l4[r]=ll;}
            *(short4v*)&VBh[cc][r0]=h4; *(short4v*)&VBl[cc][r0]=l4;
        }
#pragma unroll
        for (int q = 0; q < 4; ++q) pf[q] = pn[q];
#pragma unroll
        for (int ni = 0; ni < 4; ++ni) vcur[ni] = vnx[ni];
    }
}

// ---------------------------------------------------------------------------
// K4 (phase3 + entry): X_enter = Pe_c @ Eg[g-1] + Ve_c, then 8 recurrence
// steps x <- A[t] x + u_t with coalesced float4 out stores.
// ---------------------------------------------------------------------------
__global__ __launch_bounds__(256, 2)
void hippo_phase3(const float* __restrict__ inp, const float* __restrict__ Ag,
                  const float* __restrict__ Bst,
                  const float* __restrict__ PeT, const float* __restrict__ VeT,
                  const float* __restrict__ EgT, float* __restrict__ out)
{
    __shared__ short Ah[NB][AS], Al[NB][AS];
    __shared__ short XBh[NB][AS], XBl[NB][AS];
    __shared__ short EBh[NB][AS], EBl[NB][AS];
    __shared__ float btl[NB], itl[NB];

    const int tid = threadIdx.x, c = blockIdx.x, t0 = c * CH;
    const int g = c >> 4, j = c & (GC - 1);
    const int w = tid>>6, lane = tid&63, quad = lane>>4, l15 = lane&15;

    float4 pre[4];
    {
        const float4* Ap = (const float4*)(Ag + (size_t)t0 * 4096);
#pragma unroll
        for (int q = 0; q < 4; ++q) pre[q] = Ap[tid + q * 256];
    }

    if (c == 0) {
#pragma unroll
        for (int q = 0; q < 16; ++q) { int f = tid + q*256; XBh[f>>6][f&63] = 0; XBl[f>>6][f&63] = 0; }
    } else if (j == 0 || g == 0) {
        const float* e = (j == 0) ? (EgT + (size_t)(g-1)*4096) : (VeT + (size_t)c*4096);
#pragma unroll
        for (int q = 0; q < 4; ++q) {
            int f = tid + q*256; int b = f>>4, k0 = (f&15)*4;
            float4 v = *(const float4*)(e + b*64 + k0);
            float va[4] = {v.x,v.y,v.z,v.w};
            short4v h4, l4;
#pragma unroll
            for (int r=0;r<4;++r){short hh,ll;split_bf16(va[r],hh,ll);h4[r]=hh;l4[r]=ll;}
            *(short4v*)&XBh[b][k0] = h4; *(short4v*)&XBl[b][k0] = l4;
        }
    } else {
        const float* pe = PeT + (size_t)c*4096;
        const float* eg = EgT + (size_t)(g-1)*4096;
#pragma unroll
        for (int q = 0; q < 4; ++q) {
            int f = tid + q*256;
            int k = f & 63, m0 = (f >> 6) * 4;
            float4 v = *(const float4*)(pe + k*64 + m0);
            float vv[4] = {v.x,v.y,v.z,v.w};
#pragma unroll
            for (int rr=0;rr<4;++rr){short hh,ll;split_bf16(vv[rr],hh,ll);Ah[m0+rr][k]=hh;Al[m0+rr][k]=ll;}
        }
#pragma unroll
        for (int q = 0; q < 4; ++q) {
            int f = tid + q*256; int b = f>>4, k0 = (f&15)*4;
            float4 v = *(const float4*)(eg + b*64 + k0);
            float va[4] = {v.x,v.y,v.z,v.w};
            short4v h4, l4;
#pragma unroll
            for (int r=0;r<4;++r){short hh,ll;split_bf16(va[r],hh,ll);h4[r]=hh;l4[r]=ll;}
            *(short4v*)&EBh[b][k0] = h4; *(short4v*)&EBl[b][k0] = l4;
        }
        __syncthreads();
        const float* ve = VeT + (size_t)c*4096;
        floatx4 ax[4];
#pragma unroll
        for (int ni = 0; ni < 4; ++ni) {
            int cc = 16*ni + l15, r0 = 16*w + 4*quad;
            ax[ni] = *(const floatx4*)(ve + cc*64 + r0);
        }
#pragma unroll
        for (int kc = 0; kc < 2; ++kc) {
            int ko = 32*kc + 8*quad;
            short8 aH = *(const short8*)&Ah[16*w + l15][ko];
            short8 aL = *(const short8*)&Al[16*w + l15][ko];
#pragma unroll
            for (int ni = 0; ni < 4; ++ni) {
                int n = 16*ni + l15;
                short8 eH = *(const short8*)&EBh[n][ko];
                short8 eL = *(const short8*)&EBl[n][ko];
                ax[ni] = mfma_bf16(aH,eH,ax[ni]);
                ax[ni] = mfma_bf16(aH,eL,ax[ni]);
                ax[ni] = mfma_bf16(aL,eH,ax[ni]);
            }
        }
        __syncthreads();
#pragma unroll
        for (int ni = 0; ni < 4; ++ni) {
            int cc = 16*ni + l15, r0 = 16*w + 4*quad;
            short4v h4, l4;
#pragma unroll
            for (int r=0;r<4;++r){short hh,ll;split_bf16(ax[ni][r],hh,ll);h4[r]=hh;l4[r]=ll;}
            *(short4v*)&XBh[cc][r0] = h4; *(short4v*)&XBl[cc][r0] = l4;
        }
    }

    floatx4 acc[4];
    for (int s = 0; s < CH; ++s) {
        int t = t0 + s;
#pragma unroll
        for (int q = 0; q < 4; ++q) {
            int f = tid + q*256; int m = f>>4, k0 = (f&15)*4;
            float vv[4] = {pre[q].x,pre[q].y,pre[q].z,pre[q].w};
            short4v h4, l4;
#pragma unroll
            for (int r=0;r<4;++r){short hh,ll;split_bf16(vv[r],hh,ll);h4[r]=hh;l4[r]=ll;}
            *(short4v*)&Ah[m][k0] = h4; *(short4v*)&Al[m][k0] = l4;
        }
        if (tid < 64) { btl[tid] = Bst[(size_t)t*64 + tid]; itl[tid] = inp[(size_t)t*64 + tid]; }
        if (s + 1 < CH) {
            const float4* Ap = (const float4*)(Ag + (size_t)(t+1) * 4096);
#pragma unroll
            for (int q = 0; q < 4; ++q) pre[q] = Ap[tid + q * 256];
        }
        __syncthreads();

#pragma unroll
        for (int ni = 0; ni < 4; ++ni) {
            float ib = itl[16*ni + l15];
#pragma unroll
            for (int r = 0; r < 4; ++r) acc[ni][r] = btl[16*w + 4*quad + r] * ib;
        }
#pragma unroll
        for (int kc = 0; kc < 2; ++kc) {
            int ko = 32*kc + 8*quad;
            short8 aH = *(const short8*)&Ah[16*w + l15][ko];
            short8 aL = *(const short8*)&Al[16*w + l15][ko];
#pragma unroll
            for (int ni = 0; ni < 4; ++ni) {
                int n = 16*ni + l15;
                short8 xH = *(const short8*)&XBh[n][ko];
                short8 xL = *(const short8*)&XBl[n][ko];
                acc[ni] = mfma_bf16(aH, xH, acc[ni]);
                acc[ni] = mfma_bf16(aH, xL, acc[ni]);
                acc[ni] = mfma_bf16(aL, xH, acc[ni]);
            }
        }
        __syncthreads();
#pragma unroll
        for (int ni = 0; ni < 4; ++ni) {
            int cc = 16*ni + l15, r0 = 16*w + 4*quad;
            *(floatx4*)(out + (size_t)t*4096 + cc*64 + r0) = acc[ni];
            if (s + 1 < CH) {
                short4v h4, l4;
#pragma unroll
                for (int r=0;r<4;++r){short hh,ll;split_bf16(acc[ni][r],hh,ll);h4[r]=hh;l4[r]=ll;}
                *(short4v*)&XBh[cc][r0] = h4; *(short4v*)&XBl[cc][r0] = l4;
            }
        }
        if (s + 1 < CH) __syncthreads();
    }
}

extern "C" void kernel_launch(void* const* d_in, const int* in_sizes, int n_in,
                              void* d_out, int out_size, void* d_ws, size_t ws_size,
                              hipStream_t stream)
{
    const float* inp = (const float*)d_in[0];   // (L, B)
    const float* A   = (const float*)d_in[1];   // (L, N, N)
    const float* Bst = (const float*)d_in[2];   // (L, N)
    float* out = (float*)d_out;                  // (L, B, N)
    float* ws  = (float*)d_ws;

    float* PT  = ws;                                   // 512*4096
    float* VT  = ws + (size_t)CN * 4096;               // 512*4096
    float* GPR = ws + (size_t)2 * CN * 4096;           // 32*4096 (row-major P totals)
    float* GVT = GPR + (size_t)NG * 4096;              // 32*4096
    float* EgT = GVT + (size_t)NG * 4096;              // 32*4096

    hippo_phase1<<<CN, 256, 0, stream>>>(inp, A, Bst, PT, VT);
    hippo_groupscan<<<NG, 256, 0, stream>>>(PT, VT, GPR, GVT);
    hippo_superscan<<<1, 256, 0, stream>>>(GPR, GVT, EgT);
    hippo_phase3<<<CN, 256, 0, stream>>>(inp, A, Bst, PT, VT, EgT, out);
}